// Round 1
// baseline (53.267 us; speedup 1.0000x reference)
//
#include <hip/hip_runtime.h>

// Problem constants (from reference)
#define TOK_CODE_START 256
#define TOK_CODE_END   257
#define TOK_MEM        258
#define ADDR_KEY       206
#define MEM_STORE      455

constexpr int Bb = 16;
constexpr int Ss = 8192;
constexpr int DM = 512;

// ---------------------------------------------------------------------------
// Kernel 1: per-row scan. One block per batch row, 1024 threads, 8 tokens each.
// Computes cs = cummax(start idx), end_idx = first CODE_END, then packs
//   bit0 = valid, bit1 = mem_flag, bits[2..] = addr  (0 if neither flag)
// into one u32 per (b,s) in d_ws.
// ---------------------------------------------------------------------------
__global__ __launch_bounds__(1024) void vm_scan_kernel(
    const int* __restrict__ tok,
    const int* __restrict__ mhe_p,
    unsigned int* __restrict__ ws)
{
    const int b = blockIdx.x;
    const int t = threadIdx.x;              // 0..1023
    const int mhe = mhe_p[0];
    const int* row = tok + b * Ss;
    const int base = t * 8;

    int toks[8];
    int4 v0 = reinterpret_cast<const int4*>(row + base)[0];
    int4 v1 = reinterpret_cast<const int4*>(row + base)[1];
    toks[0] = v0.x; toks[1] = v0.y; toks[2] = v0.z; toks[3] = v0.w;
    toks[4] = v1.x; toks[5] = v1.y; toks[6] = v1.z; toks[7] = v1.w;

    // local chunk summaries
    int lmax = -1;      // max index of CODE_START in chunk (-1 if none)
    int lend = Ss;      // min index of CODE_END in chunk (Ss if none)
    #pragma unroll
    for (int k = 0; k < 8; ++k) {
        int idx = base + k;
        if (toks[k] == TOK_CODE_START) lmax = idx;            // idx increasing -> max
        if (toks[k] == TOK_CODE_END && lend == Ss) lend = idx; // first
    }

    __shared__ int smax[1024];
    __shared__ int smin[1024];
    smax[t] = lmax;
    smin[t] = lend;
    __syncthreads();

    // block min-reduce -> row-level first CODE_END
    for (int off = 512; off > 0; off >>= 1) {
        if (t < off) smin[t] = min(smin[t], smin[t + off]);
        __syncthreads();
    }
    const int end_idx = smin[0];

    // inclusive Hillis-Steele max-scan over per-thread chunk maxima
    for (int off = 1; off < 1024; off <<= 1) {
        int u = (t >= off) ? smax[t - off] : -1;
        __syncthreads();
        if (u > smax[t]) smax[t] = u;
        __syncthreads();
    }
    int run = (t > 0) ? smax[t - 1] : -1;   // exclusive prefix max

    unsigned int pk[8];
    #pragma unroll
    for (int k = 0; k < 8; ++k) {
        int idx = base + k;
        int tv = toks[k];
        if (tv == TOK_CODE_START) run = idx;   // inclusive update
        int cs = run;
        int addr = idx - cs - 1;
        bool valid = (cs >= 0) && (idx < end_idx) && (tv < 256) && (addr >= 0);
        bool memf  = (tv == TOK_MEM) && (idx < mhe);
        unsigned int w = (valid ? 1u : 0u) | (memf ? 2u : 0u);
        if (valid) w |= ((unsigned int)addr << 2);
        pk[k] = w;
    }
    uint4* wr = reinterpret_cast<uint4*>(ws + b * Ss + base);
    wr[0] = make_uint4(pk[0], pk[1], pk[2], pk[3]);
    wr[1] = make_uint4(pk[4], pk[5], pk[6], pk[7]);
}

// ---------------------------------------------------------------------------
// Kernel 2: gather + mask overwrite. One float4 (4 dims) per work item.
// 128 consecutive threads share one (b,s) -> packed word is wave-uniform,
// mask branch is non-divergent and skipped for ~96% of positions.
// ---------------------------------------------------------------------------
__global__ __launch_bounds__(256) void vm_gather_kernel(
    const int* __restrict__ tok,
    const float* __restrict__ emb,
    const unsigned int* __restrict__ ws,
    float4* __restrict__ out)
{
    const long long total = (long long)Bb * Ss * (DM / 4);   // 16,777,216
    const long long stride = (long long)gridDim.x * blockDim.x;
    for (long long w = (long long)blockIdx.x * blockDim.x + threadIdx.x;
         w < total; w += stride) {
        int bs = (int)(w >> 7);          // DM/4 == 128 quads per (b,s)
        int dq = (int)(w & 127);
        int d0 = dq << 2;
        int tk = tok[bs];
        unsigned int pw = ws[bs];
        float4 v = reinterpret_cast<const float4*>(emb)[tk * (DM / 4) + dq];
        if (pw) {                                    // wave-uniform branch
            bool valid = (pw & 1u) != 0u;
            bool memf  = (pw & 2u) != 0u;
            int addr = (int)(pw >> 2);
            int p0 = ADDR_KEY      + (addr & 15);
            int p1 = ADDR_KEY + 16 + ((addr >> 4) & 15);
            int p2 = ADDR_KEY + 32 + ((addr >> 8) & 15);
            int d;
            d = d0 + 0; if ((valid && (d == p0 || d == p1 || d == p2)) || (memf && d == MEM_STORE)) v.x = 1.0f;
            d = d0 + 1; if ((valid && (d == p0 || d == p1 || d == p2)) || (memf && d == MEM_STORE)) v.y = 1.0f;
            d = d0 + 2; if ((valid && (d == p0 || d == p1 || d == p2)) || (memf && d == MEM_STORE)) v.z = 1.0f;
            d = d0 + 3; if ((valid && (d == p0 || d == p1 || d == p2)) || (memf && d == MEM_STORE)) v.w = 1.0f;
        }
        out[w] = v;
    }
}

extern "C" void kernel_launch(void* const* d_in, const int* in_sizes, int n_in,
                              void* d_out, int out_size, void* d_ws, size_t ws_size,
                              hipStream_t stream) {
    const int* tok = (const int*)d_in[0];
    const float* emb = (const float*)d_in[1];
    const int* mhe = (const int*)d_in[2];
    unsigned int* ws = (unsigned int*)d_ws;   // needs Bb*Ss*4 = 512 KiB
    float4* out = (float4*)d_out;

    vm_scan_kernel<<<Bb, 1024, 0, stream>>>(tok, mhe, ws);
    vm_gather_kernel<<<2048, 256, 0, stream>>>(tok, emb, ws, out);
}

// Round 3
// 51.427 us; speedup vs baseline: 1.0358x; 1.0358x over previous
//
#include <hip/hip_runtime.h>

// Problem constants (from reference)
#define TOK_CODE_START 256
#define TOK_CODE_END   257
#define TOK_MEM        258
#define ADDR_KEY       206
#define MEM_STORE      455

constexpr int Bb = 16;
constexpr int Ss = 8192;
constexpr int DM = 512;

typedef float f32x4 __attribute__((ext_vector_type(4)));

// ---------------------------------------------------------------------------
// Kernel 1: per-row scan. One block per batch row, 1024 threads (16 waves),
// 8 tokens per thread. Wave-level shuffle scan (no barriers) + one LDS round
// for the 16 wave carries. Packs per (b,s):
//   bits[0..8]  = token id (0..271)
//   bit 9       = valid
//   bit 10      = mem_flag
//   bits[11..]  = addr (when valid)
// into one u32 in d_ws.
// ---------------------------------------------------------------------------
__global__ __launch_bounds__(1024) void vm_scan_kernel(
    const int* __restrict__ tok,
    const int* __restrict__ mhe_p,
    unsigned int* __restrict__ ws)
{
    const int b = blockIdx.x;
    const int t = threadIdx.x;              // 0..1023
    const int lane = t & 63;
    const int wid = t >> 6;                 // 0..15
    const int mhe = mhe_p[0];
    const int* row = tok + b * Ss;
    const int base = t * 8;

    int toks[8];
    int4 v0 = reinterpret_cast<const int4*>(row + base)[0];
    int4 v1 = reinterpret_cast<const int4*>(row + base)[1];
    toks[0] = v0.x; toks[1] = v0.y; toks[2] = v0.z; toks[3] = v0.w;
    toks[4] = v1.x; toks[5] = v1.y; toks[6] = v1.z; toks[7] = v1.w;

    // per-thread chunk summaries
    int lmax = -1;      // max index of CODE_START in my 8 (-1 if none)
    int lend = Ss;      // first index of CODE_END in my 8 (Ss if none)
    #pragma unroll
    for (int k = 0; k < 8; ++k) {
        int idx = base + k;
        if (toks[k] == TOK_CODE_START) lmax = idx;             // idx increasing
        if (toks[k] == TOK_CODE_END && lend == Ss) lend = idx; // first
    }

    // wave inclusive max-scan of lmax (6 shuffle steps, no barriers)
    #pragma unroll
    for (int off = 1; off < 64; off <<= 1) {
        int u = __shfl_up(lmax, off);
        if (lane >= off && u > lmax) lmax = u;
    }
    // exclusive version for this thread
    int excl = __shfl_up(lmax, 1);
    if (lane == 0) excl = -1;

    // wave min-reduce of lend (all lanes get the wave min)
    #pragma unroll
    for (int off = 32; off > 0; off >>= 1) {
        int u = __shfl_xor(lend, off);
        if (u < lend) lend = u;
    }

    __shared__ int wmax[16];   // per-wave inclusive total (lane 63's value)
    __shared__ int wend[16];   // per-wave min first-end
    if (lane == 63) wmax[wid] = lmax;
    if (lane == 0)  wend[wid] = lend;
    __syncthreads();

    int carry = -1;
    #pragma unroll
    for (int j = 0; j < 16; ++j)
        if (j < wid && wmax[j] > carry) carry = wmax[j];
    int end_idx = Ss;
    #pragma unroll
    for (int j = 0; j < 16; ++j)
        if (wend[j] < end_idx) end_idx = wend[j];

    int run = (carry > excl) ? carry : excl;   // latest start strictly before my chunk

    unsigned int pk[8];
    #pragma unroll
    for (int k = 0; k < 8; ++k) {
        int idx = base + k;
        int tv = toks[k];
        if (tv == TOK_CODE_START) run = idx;   // inclusive cummax update
        int cs = run;
        int addr = idx - cs - 1;
        bool valid = (cs >= 0) && (idx < end_idx) && (tv < 256) && (addr >= 0);
        bool memf  = (tv == TOK_MEM) && (idx < mhe);
        unsigned int w = (unsigned int)tv;                       // bits 0..8
        if (valid) w |= (1u << 9) | ((unsigned int)addr << 11);
        if (memf)  w |= (1u << 10);
        pk[k] = w;
    }
    uint4* wr = reinterpret_cast<uint4*>(ws + b * Ss + base);
    wr[0] = make_uint4(pk[0], pk[1], pk[2], pk[3]);
    wr[1] = make_uint4(pk[4], pk[5], pk[6], pk[7]);
}

// ---------------------------------------------------------------------------
// Kernel 2: gather + mask overwrite. One float4 (4 dims) per work item.
// 128 consecutive threads share one (b,s) -> packed word is ~wave-uniform;
// mask branch skipped for ~96% of positions. Nontemporal streaming stores.
// ---------------------------------------------------------------------------
__global__ __launch_bounds__(256) void vm_gather_kernel(
    const f32x4* __restrict__ emb,
    const unsigned int* __restrict__ ws,
    f32x4* __restrict__ out)
{
    const int total = Bb * Ss * (DM / 4);    // 16,777,216
    const int stride = gridDim.x * blockDim.x;
    for (int w = blockIdx.x * blockDim.x + threadIdx.x; w < total; w += stride) {
        int bs = w >> 7;                     // 128 quads per (b,s)
        int dq = w & 127;
        unsigned int pw = ws[bs];
        int tk = (int)(pw & 511u);
        f32x4 v = emb[tk * (DM / 4) + dq];
        unsigned int flags = pw >> 9;
        if (flags) {                         // ~wave-uniform branch
            bool valid = (flags & 1u) != 0u;
            bool memf  = (flags & 2u) != 0u;
            int addr = (int)(flags >> 2);
            int p0 = ADDR_KEY      + (addr & 15);
            int p1 = ADDR_KEY + 16 + ((addr >> 4) & 15);
            int p2 = ADDR_KEY + 32 + ((addr >> 8) & 15);
            int d0 = dq << 2;
            #pragma unroll
            for (int j = 0; j < 4; ++j) {
                int d = d0 + j;
                if ((valid && (d == p0 || d == p1 || d == p2)) ||
                    (memf && d == MEM_STORE)) v[j] = 1.0f;
            }
        }
        __builtin_nontemporal_store(v, &out[w]);
    }
}

extern "C" void kernel_launch(void* const* d_in, const int* in_sizes, int n_in,
                              void* d_out, int out_size, void* d_ws, size_t ws_size,
                              hipStream_t stream) {
    const int* tok = (const int*)d_in[0];
    const float* emb = (const float*)d_in[1];
    const int* mhe = (const int*)d_in[2];
    unsigned int* ws = (unsigned int*)d_ws;   // needs Bb*Ss*4 = 512 KiB
    f32x4* out = (f32x4*)d_out;

    vm_scan_kernel<<<Bb, 1024, 0, stream>>>(tok, mhe, ws);
    vm_gather_kernel<<<2048, 256, 0, stream>>>((const f32x4*)emb, ws, out);
}